// Round 1
// baseline (335.888 us; speedup 1.0000x reference)
//
#include <hip/hip_runtime.h>
#include <math.h>

#define R_BINS 64
#define Z_BINS 64
#define NBINS (R_BINS * Z_BINS)
#define BLOCK 512
#define WAVES_PER_BLOCK 8
#define GRID 1024
#define NPART GRID                        // one 16 KB partial slab per block

#define RBLOCK 512
#define RGRID (NBINS / 64)                // 64 reduce blocks, 64 bins each

static constexpr float DR     = 10.0f / 64.0f;   // 0.15625 (exact in fp32)
static constexpr float DZ     = 4.0f  / 64.0f;   // 0.0625  (exact in fp32)
static constexpr float INV_DR = 6.4f;
static constexpr float INV_DZ = 16.0f;

// Streaming + binning identical to the proven 118 us version; the ONLY change
// is the drain: instead of 1.6M global fp32 atomics into 16 KB of address
// space (L2 same-line serialization, ~60 us), each block plain-stores its
// private histogram into partials[blockIdx][*] with coalesced float4 stores.
__global__ __launch_bounds__(BLOCK) void hist_kernel(const float4* __restrict__ pos4,
                                                     const float* __restrict__ mass,
                                                     float* __restrict__ partials,
                                                     int nchunks) {
    __shared__ float lbins[NBINS];                    // 16 KB
    __shared__ float4 stage[WAVES_PER_BLOCK][192];    // 24 KB (3 KB / wave)

    const int lane = threadIdx.x & 63;
    const int w    = threadIdx.x >> 6;

    for (int b = threadIdx.x; b < NBINS; b += BLOCK) lbins[b] = 0.0f;
    __syncthreads();

    const int totalWaves = gridDim.x * WAVES_PER_BLOCK;
    float* s = (float*)&stage[w][0];                  // 768 floats = 256 particles

    for (int c = blockIdx.x * WAVES_PER_BLOCK + w; c < nchunks; c += totalWaves) {
        const float4* pb = pos4 + (size_t)192 * c;
        const float4 f0 = pb[lane];
        const float4 f1 = pb[64 + lane];
        const float4 f2 = pb[128 + lane];

        const float* mb = mass + (size_t)256 * c;
        const float m0 = mb[lane];
        const float m1 = mb[64 + lane];
        const float m2 = mb[128 + lane];
        const float m3 = mb[192 + lane];

        stage[w][lane]       = f0;
        stage[w][64 + lane]  = f1;
        stage[w][128 + lane] = f2;
        // Wave-local write->read ordering: LDS pipe is in-order per wave; pin
        // compiler ordering + drain lgkm before cross-lane readback.
        __asm__ volatile("s_waitcnt lgkmcnt(0)" ::: "memory");
        __builtin_amdgcn_wave_barrier();

        const float ms[4] = {m0, m1, m2, m3};
#pragma unroll
        for (int k = 0; k < 4; ++k) {
            const int p = 64 * k + lane;              // strided particle pick
            const float x = s[3 * p];
            const float y = s[3 * p + 1];
            const float z = s[3 * p + 2];
            const float r = sqrtf(x * x + y * y);
            const int i = (int)(r * INV_DR);          // r >= 0, trunc == floor
            const int j = (int)floorf((z + 2.0f) * INV_DZ);
            if (i < R_BINS && (unsigned)j < (unsigned)Z_BINS) {
                atomicAdd(&lbins[i * Z_BINS + j], ms[k]);
            }
        }
        // read-before-next-write ordering (in-order LDS pipe; pin compiler)
        __asm__ volatile("" ::: "memory");
        __builtin_amdgcn_wave_barrier();
    }

    __syncthreads();
    // Contention-free drain: 2 coalesced float4 stores/thread, 16 KB/block.
    float4* p4 = (float4*)(partials + (size_t)blockIdx.x * NBINS);
    const float4* l4 = (const float4*)lbins;
    p4[threadIdx.x]         = l4[threadIdx.x];
    p4[BLOCK + threadIdx.x] = l4[BLOCK + threadIdx.x];
}

// Tail for n % 256 != 0 (not hit at N=16777216; kept for robustness).
// Runs AFTER hist_kernel on the same stream, so atomics into slab 0 are safe.
__global__ void tail_kernel(const float* __restrict__ pos,
                            const float* __restrict__ mass,
                            float* __restrict__ partials,
                            int start, int n) {
    const int t = start + blockIdx.x * blockDim.x + threadIdx.x;
    if (t < n) {
        const float x = pos[3 * t], y = pos[3 * t + 1], z = pos[3 * t + 2];
        const float r = sqrtf(x * x + y * y);
        const int i = (int)(r * INV_DR);
        const int j = (int)floorf((z + 2.0f) * INV_DZ);
        if (i < R_BINS && (unsigned)j < (unsigned)Z_BINS) {
            atomicAdd(&partials[i * Z_BINS + j], mass[t]);
        }
    }
}

// Fused reduce (1024 slabs -> 1 histogram) + volume divide.
// 64 blocks x 512 threads: block bb owns bins [bb*64, bb*64+64).
// Thread (grp = t>>6, bl = t&63) sums slabs s === grp (mod 8); each wave's
// 64 lanes read 256 contiguous bytes -> fully coalesced. 4 independent
// accumulators keep >=4 loads in flight per thread (16.8 MB total read).
__global__ __launch_bounds__(RBLOCK) void reduce_finalize(const float* __restrict__ partials,
                                                          float* __restrict__ out) {
    __shared__ float red[RBLOCK];
    const int t   = threadIdx.x;
    const int bl  = t & 63;
    const int grp = t >> 6;                       // 0..7
    const int bin = blockIdx.x * 64 + bl;

    float a0 = 0.0f, a1 = 0.0f, a2 = 0.0f, a3 = 0.0f;
    for (int sb = grp; sb < NPART; sb += 32) {    // 32 iters, 4 slabs each
        a0 += partials[(size_t)(sb)      * NBINS + bin];
        a1 += partials[(size_t)(sb + 8)  * NBINS + bin];
        a2 += partials[(size_t)(sb + 16) * NBINS + bin];
        a3 += partials[(size_t)(sb + 24) * NBINS + bin];
    }
    red[t] = (a0 + a1) + (a2 + a3);
    __syncthreads();

    if (t < 64) {
        float acc = 0.0f;
#pragma unroll
        for (int g = 0; g < 8; ++g) acc += red[g * 64 + bl];
        const int i = bin >> 6;                   // == blockIdx.x (r-bin index)
        const float r0 = (float)i * DR;
        const float r1 = (float)(i + 1) * DR;
        const float area = (float)M_PI * (r1 * r1 - r0 * r0);
        out[bin] = acc / (area * DZ);
    }
}

extern "C" void kernel_launch(void* const* d_in, const int* in_sizes, int n_in,
                              void* d_out, int out_size, void* d_ws, size_t ws_size,
                              hipStream_t stream) {
    const float* positions = (const float*)d_in[0];  // (N,3) interleaved xyz
    const float* masses    = (const float*)d_in[1];  // (N,)
    float* out      = (float*)d_out;                 // (64*64,)
    float* partials = (float*)d_ws;                  // NPART*NBINS*4 = 16 MiB
    // ws is poisoned 0xAA each call, but every slab is fully overwritten by
    // hist_kernel before reduce_finalize reads it -> no memset needed.
    // (Observed ws poison fill = 786432 KB -> ws_size = 768 MiB >> 16 MiB.)

    const int n = in_sizes[1];
    const int nchunks = n / 256;
    const int rem = n - nchunks * 256;

    hist_kernel<<<GRID, BLOCK, 0, stream>>>((const float4*)positions, masses,
                                            partials, nchunks);
    if (rem > 0) {
        tail_kernel<<<(rem + 255) / 256, 256, 0, stream>>>(positions, masses,
                                                           partials, nchunks * 256, n);
    }
    reduce_finalize<<<RGRID, RBLOCK, 0, stream>>>(partials, out);
}

// Round 2
// 334.693 us; speedup vs baseline: 1.0036x; 1.0036x over previous
//
#include <hip/hip_runtime.h>
#include <math.h>

#define R_BINS 64
#define Z_BINS 64
#define NBINS (R_BINS * Z_BINS)
#define BLOCK 512
#define GRID 1024
#define NPART GRID                        // one 16 KB partial slab per block

#define RBLOCK 512
#define RGRID (NBINS / 64)                // 64 reduce blocks, 64 bins each

static constexpr float DR     = 10.0f / 64.0f;   // 0.15625 (exact in fp32)
static constexpr float DZ     = 4.0f  / 64.0f;   // 0.0625  (exact in fp32)
static constexpr float INV_DR = 6.4f;
static constexpr float INV_DZ = 16.0f;

__device__ __forceinline__ void bin1(float x, float y, float z, float m,
                                     float* __restrict__ lbins) {
    const float r = sqrtf(x * x + y * y);
    const int i = (int)(r * INV_DR);              // r >= 0, trunc == floor
    const int j = (int)floorf((z + 2.0f) * INV_DZ);
    if (i < R_BINS && (unsigned)j < (unsigned)Z_BINS) {
        atomicAdd(&lbins[i * Z_BINS + j], m);
    }
}

// v2: no LDS transpose stage. 48 B of interleaved xyz = exactly 4 particles,
// so 3 consecutive float4 loads per thread deliver all coordinates lane-local
// in registers: (x0 y0 z0 x1)(y1 z1 x2 y2)(z2 x3 y3 z3); masses are one
// float4. No cross-lane exchange, no lgkmcnt waits, no wave_barriers ->
// iterations are independent and loads pipeline across the grid-stride loop
// instead of exposing full memory latency once per 256-particle chunk.
__global__ __launch_bounds__(BLOCK) void hist_kernel(const float4* __restrict__ pos4,
                                                     const float4* __restrict__ mass4,
                                                     float* __restrict__ partials,
                                                     int ngroups) {
    __shared__ float lbins[NBINS];                // 16 KB

    for (int b = threadIdx.x; b < NBINS; b += BLOCK) lbins[b] = 0.0f;
    __syncthreads();

    const int total = gridDim.x * BLOCK;
#pragma unroll 2
    for (int g = blockIdx.x * BLOCK + threadIdx.x; g < ngroups; g += total) {
        const size_t gb = (size_t)g * 3;
        const float4 q0 = pos4[gb];
        const float4 q1 = pos4[gb + 1];
        const float4 q2 = pos4[gb + 2];
        const float4 m  = mass4[g];

        bin1(q0.x, q0.y, q0.z, m.x, lbins);
        bin1(q0.w, q1.x, q1.y, m.y, lbins);
        bin1(q1.z, q1.w, q2.x, m.z, lbins);
        bin1(q2.y, q2.z, q2.w, m.w, lbins);
    }

    __syncthreads();
    // Contention-free drain: 2 coalesced float4 stores/thread, 16 KB/block.
    float4* p4 = (float4*)(partials + (size_t)blockIdx.x * NBINS);
    const float4* l4 = (const float4*)lbins;
    p4[threadIdx.x]         = l4[threadIdx.x];
    p4[BLOCK + threadIdx.x] = l4[BLOCK + threadIdx.x];
}

// Tail for n % 4 != 0 (not hit at N=16777216; kept for robustness).
// Runs AFTER hist_kernel on the same stream, so atomics into slab 0 are safe.
__global__ void tail_kernel(const float* __restrict__ pos,
                            const float* __restrict__ mass,
                            float* __restrict__ partials,
                            int start, int n) {
    const int t = start + blockIdx.x * blockDim.x + threadIdx.x;
    if (t < n) {
        const float x = pos[3 * t], y = pos[3 * t + 1], z = pos[3 * t + 2];
        const float r = sqrtf(x * x + y * y);
        const int i = (int)(r * INV_DR);
        const int j = (int)floorf((z + 2.0f) * INV_DZ);
        if (i < R_BINS && (unsigned)j < (unsigned)Z_BINS) {
            atomicAdd(&partials[i * Z_BINS + j], mass[t]);
        }
    }
}

// Fused reduce (1024 slabs -> 1 histogram) + volume divide.
// 64 blocks x 512 threads: block bb owns bins [bb*64, bb*64+64).
// Thread (grp = t>>6, bl = t&63) sums slabs s === grp (mod 8); each wave's
// 64 lanes read 256 contiguous bytes -> fully coalesced. 4 independent
// accumulators keep >=4 loads in flight per thread (16.8 MB total read).
__global__ __launch_bounds__(RBLOCK) void reduce_finalize(const float* __restrict__ partials,
                                                          float* __restrict__ out) {
    __shared__ float red[RBLOCK];
    const int t   = threadIdx.x;
    const int bl  = t & 63;
    const int grp = t >> 6;                       // 0..7
    const int bin = blockIdx.x * 64 + bl;

    float a0 = 0.0f, a1 = 0.0f, a2 = 0.0f, a3 = 0.0f;
    for (int sb = grp; sb < NPART; sb += 32) {    // 32 iters, 4 slabs each
        a0 += partials[(size_t)(sb)      * NBINS + bin];
        a1 += partials[(size_t)(sb + 8)  * NBINS + bin];
        a2 += partials[(size_t)(sb + 16) * NBINS + bin];
        a3 += partials[(size_t)(sb + 24) * NBINS + bin];
    }
    red[t] = (a0 + a1) + (a2 + a3);
    __syncthreads();

    if (t < 64) {
        float acc = 0.0f;
#pragma unroll
        for (int g = 0; g < 8; ++g) acc += red[g * 64 + bl];
        const int i = bin >> 6;                   // == blockIdx.x (r-bin index)
        const float r0 = (float)i * DR;
        const float r1 = (float)(i + 1) * DR;
        const float area = (float)M_PI * (r1 * r1 - r0 * r0);
        out[bin] = acc / (area * DZ);
    }
}

extern "C" void kernel_launch(void* const* d_in, const int* in_sizes, int n_in,
                              void* d_out, int out_size, void* d_ws, size_t ws_size,
                              hipStream_t stream) {
    const float* positions = (const float*)d_in[0];  // (N,3) interleaved xyz
    const float* masses    = (const float*)d_in[1];  // (N,)
    float* out      = (float*)d_out;                 // (64*64,)
    float* partials = (float*)d_ws;                  // NPART*NBINS*4 = 16 MiB
    // ws is poisoned 0xAA each call, but every slab is fully overwritten by
    // hist_kernel before reduce_finalize reads it -> no memset needed.

    const int n = in_sizes[1];
    const int ngroups = n / 4;                       // 4 particles (48 B) / group
    const int rem = n - ngroups * 4;

    hist_kernel<<<GRID, BLOCK, 0, stream>>>((const float4*)positions,
                                            (const float4*)masses,
                                            partials, ngroups);
    if (rem > 0) {
        tail_kernel<<<(rem + 255) / 256, 256, 0, stream>>>(positions, masses,
                                                           partials, ngroups * 4, n);
    }
    reduce_finalize<<<RGRID, RBLOCK, 0, stream>>>(partials, out);
}

// Round 3
// 327.499 us; speedup vs baseline: 1.0256x; 1.0220x over previous
//
#include <hip/hip_runtime.h>
#include <math.h>

#define R_BINS 64
#define Z_BINS 64
#define NBINS (R_BINS * Z_BINS)
#define BLOCK 512
#define GRID 1024

static constexpr float DR     = 10.0f / 64.0f;   // 0.15625 (exact in fp32)
static constexpr float DZ     = 4.0f  / 64.0f;   // 0.0625  (exact in fp32)
static constexpr float INV_DR = 6.4f;
static constexpr float INV_DZ = 16.0f;

__device__ __forceinline__ void bin1(float x, float y, float z, float m,
                                     float* __restrict__ lbins) {
    const float r = sqrtf(x * x + y * y);
    const int i = (int)(r * INV_DR);              // r >= 0, trunc == floor
    const int j = (int)floorf((z + 2.0f) * INV_DZ);
    if (i < R_BINS && (unsigned)j < (unsigned)Z_BINS) {
        atomicAdd(&lbins[i * Z_BINS + j], m);
    }
}

// v4: two memory-path probes (everything CU-side is known-irrelevant: three
// structurally different versions all pinned at 118 us, VALUBusy 10%).
//  (a) block-chunked contiguous schedule: block b owns groups
//      [b*4096, (b+1)*4096) and streams them sequentially (192 KB pos +
//      64 KB mass contiguous per block), instead of grid-stride where all
//      1024 blocks cluster in one 24 MB window and jump 24 MB per iter.
//  (b) hand-grouped double-issue: 8 float4 loads in flight per wave
//      (VGPR_Count=12 proved the compiler was serializing ~4).
// Drain reverted to round-0 skip-zero global atomics (measured free; the
// partials+reduce round-trip cost ~8 us of total).
__global__ __launch_bounds__(BLOCK) void hist_kernel(const float4* __restrict__ pos4,
                                                     const float4* __restrict__ mass4,
                                                     float* __restrict__ gbins,
                                                     int ngroups) {
    __shared__ float lbins[NBINS];                // 16 KB

    for (int b = threadIdx.x; b < NBINS; b += BLOCK) lbins[b] = 0.0f;
    __syncthreads();

    // Block-chunked ownership: gpb groups per block, contiguous.
    const int gpb   = (ngroups + GRID - 1) / GRID;        // 4096 at N=16.7M
    const int gbeg  = blockIdx.x * gpb;
    const int gend  = min(gbeg + gpb, ngroups);

    int g = gbeg + threadIdx.x;
    // steady-state: pairs of iterations with all 8 loads issued up front
    for (; g + BLOCK < gend; g += 2 * BLOCK) {
        const size_t ga = (size_t)g * 3;
        const size_t gb = (size_t)(g + BLOCK) * 3;
        const float4 a0 = pos4[ga];
        const float4 a1 = pos4[ga + 1];
        const float4 a2 = pos4[ga + 2];
        const float4 b0 = pos4[gb];
        const float4 b1 = pos4[gb + 1];
        const float4 b2 = pos4[gb + 2];
        const float4 am = mass4[g];
        const float4 bm = mass4[g + BLOCK];

        bin1(a0.x, a0.y, a0.z, am.x, lbins);
        bin1(a0.w, a1.x, a1.y, am.y, lbins);
        bin1(a1.z, a1.w, a2.x, am.z, lbins);
        bin1(a2.y, a2.z, a2.w, am.w, lbins);

        bin1(b0.x, b0.y, b0.z, bm.x, lbins);
        bin1(b0.w, b1.x, b1.y, bm.y, lbins);
        bin1(b1.z, b1.w, b2.x, bm.z, lbins);
        bin1(b2.y, b2.z, b2.w, bm.w, lbins);
    }
    // remainder (0 or 1 iteration at these sizes)
    for (; g < gend; g += BLOCK) {
        const size_t ga = (size_t)g * 3;
        const float4 a0 = pos4[ga];
        const float4 a1 = pos4[ga + 1];
        const float4 a2 = pos4[ga + 2];
        const float4 am = mass4[g];
        bin1(a0.x, a0.y, a0.z, am.x, lbins);
        bin1(a0.w, a1.x, a1.y, am.y, lbins);
        bin1(a1.z, a1.w, a2.x, am.z, lbins);
        bin1(a2.y, a2.z, a2.w, am.w, lbins);
    }

    __syncthreads();
    // Skip-zero atomic drain (measured-free in round 0: overlaps fully).
    for (int b = threadIdx.x; b < NBINS; b += BLOCK) {
        const float v = lbins[b];
        if (v != 0.0f) atomicAdd(&gbins[b], v);
    }
}

// Tail for n % 4 != 0 (not hit at N=16777216; kept for robustness).
__global__ void tail_kernel(const float* __restrict__ pos,
                            const float* __restrict__ mass,
                            float* __restrict__ gbins,
                            int start, int n) {
    const int t = start + blockIdx.x * blockDim.x + threadIdx.x;
    if (t < n) {
        const float x = pos[3 * t], y = pos[3 * t + 1], z = pos[3 * t + 2];
        const float r = sqrtf(x * x + y * y);
        const int i = (int)(r * INV_DR);
        const int j = (int)floorf((z + 2.0f) * INV_DZ);
        if (i < R_BINS && (unsigned)j < (unsigned)Z_BINS) {
            atomicAdd(&gbins[i * Z_BINS + j], mass[t]);
        }
    }
}

__global__ __launch_bounds__(256) void finalize_kernel(const float* __restrict__ gbins,
                                                       float* __restrict__ out) {
    const int idx = blockIdx.x * blockDim.x + threadIdx.x;
    if (idx < NBINS) {
        const int i = idx / Z_BINS;
        const float r0 = (float)i * DR;
        const float r1 = (float)(i + 1) * DR;
        const float area = (float)M_PI * (r1 * r1 - r0 * r0);
        out[idx] = gbins[idx] / (area * DZ);
    }
}

extern "C" void kernel_launch(void* const* d_in, const int* in_sizes, int n_in,
                              void* d_out, int out_size, void* d_ws, size_t ws_size,
                              hipStream_t stream) {
    const float* positions = (const float*)d_in[0];  // (N,3) interleaved xyz
    const float* masses    = (const float*)d_in[1];  // (N,)
    float* out   = (float*)d_out;                    // (64*64,)
    float* gbins = (float*)d_ws;                     // 16 KB accumulator

    const int n = in_sizes[1];
    const int ngroups = n / 4;                       // 4 particles (48 B) / group
    const int rem = n - ngroups * 4;

    // d_ws is re-poisoned to 0xAA before every timed call — zero it.
    hipMemsetAsync(gbins, 0, NBINS * sizeof(float), stream);

    hist_kernel<<<GRID, BLOCK, 0, stream>>>((const float4*)positions,
                                            (const float4*)masses,
                                            gbins, ngroups);
    if (rem > 0) {
        tail_kernel<<<(rem + 255) / 256, 256, 0, stream>>>(positions, masses,
                                                           gbins, ngroups * 4, n);
    }
    finalize_kernel<<<(NBINS + 255) / 256, 256, 0, stream>>>(gbins, out);
}